// Round 12
// baseline (590.478 us; speedup 1.0000x reference)
//
#include <hip/hip_runtime.h>

typedef unsigned int uint;
typedef unsigned short ushort;
typedef __attribute__((ext_vector_type(4))) float f32x4;
typedef __attribute__((ext_vector_type(2))) float f32x2;
typedef __attribute__((ext_vector_type(8))) short bf16x8;

#define N_NODES 50000
#define DIM 128
#define HEADS 2
#define HD 256      // HEADS*DIM
#define MLP 512
#define DEPTH 2
#define CAP 96      // max in-degree bucket capacity (Poisson(16): P(>96) ~ 1e-40)

// ---- bf16 helpers (manual, RNE) ----
__device__ __forceinline__ uint f2bf(float f) {
    uint u = __float_as_uint(f);
    return (u + 0x7FFFu + ((u >> 16) & 1u)) >> 16;   // round-nearest-even
}
__device__ __forceinline__ f32x2 bfpair(uint u) {
    f32x2 r;
    r.x = __uint_as_float(u << 16);
    r.y = __uint_as_float(u & 0xFFFF0000u);
    return r;
}

__device__ __forceinline__ float gelu_tanh(float x) {
    float t = 0.7978845608028654f * (x + 0.044715f * x * x * x);
    float e = __expf(2.0f * t);
    float th = 1.0f - 2.0f / (e + 1.0f);   // tanh(t), overflow-safe
    return 0.5f * x * (1.0f + th);
}

// ------- one-shot weight convert+transpose (all 5 weights, bf16) -------------
__global__ __launch_bounds__(256) void wconv_all(
    const float* __restrict__ Wl, const float* __restrict__ Wr,
    const float* __restrict__ pW, const float* __restrict__ W1,
    const float* __restrict__ W2, ushort* __restrict__ WlWr_t,
    ushort* __restrict__ pW_t, ushort* __restrict__ W1_t,
    ushort* __restrict__ W2_t)
{
    int i = blockIdx.x * 256 + threadIdx.x;
    if (i < 65536) {                       // Wl [D][128][256] -> [D][512][128] rows 0..255
        int l = i >> 15, rem = i & 32767;
        int k = rem >> 8, m = rem & 255;
        WlWr_t[l * 65536 + m * 128 + k] = (ushort)f2bf(Wl[i]);
    } else if (i < 131072) {               // Wr -> rows 256..511
        int j = i - 65536;
        int l = j >> 15, rem = j & 32767;
        int k = rem >> 8, m = rem & 255;
        WlWr_t[l * 65536 + (m + 256) * 128 + k] = (ushort)f2bf(Wr[j]);
    } else if (i < 196608) {               // proj [D][256][128] -> [D][128][256]
        int j = i - 131072;
        int l = j >> 15, rem = j & 32767;
        int k = rem >> 7, m = rem & 127;
        pW_t[l * 32768 + m * 256 + k] = (ushort)f2bf(pW[j]);
    } else if (i < 327680) {               // W1 [D][128][512] -> [D][512][128]
        int j = i - 196608;
        int l = j >> 16, rem = j & 65535;
        int k = rem >> 9, m = rem & 511;
        W1_t[l * 65536 + m * 128 + k] = (ushort)f2bf(W1[j]);
    } else if (i < 458752) {               // W2 [D][512][128] -> [D][128][512]
        int j = i - 327680;
        int l = j >> 16, rem = j & 65535;
        int k = rem >> 7, m = rem & 127;
        W2_t[l * 65536 + m * 512 + k] = (ushort)f2bf(W2[j]);
    }
}

// -------- LN-fused K=128 GEMM: C = epi(LN(X) @ Bt^T + bias) -------------------
// X fp32 [Nr][128]. Per block: LN+convert the 128-row A-tile into LDS (bf16),
// stage the 64-col B-tile full-K into LDS, ONE barrier, then 32 MFMAs/wave
// with zero further syncs. 128x64 tile, 2x2 waves. LDS 52 KB -> 3 blocks/CU.
// EPI: 0=bias->bf16, 1=bias+gelu->bf16.
template<int EPI>
__global__ __launch_bounds__(256) void gemm_ln(
    const float* __restrict__ X, const ushort* __restrict__ Bt,
    const float* __restrict__ lng, const float* __restrict__ lnb,
    const float* __restrict__ bias, const float* __restrict__ bias2, int bsplit,
    ushort* __restrict__ Cout, int Nr, int M)
{
    __shared__ ushort As[128 * 136];   // 34.8 KB, stride 136 ush (pad 8)
    __shared__ ushort Bs[64 * 136];    // 17.4 KB
    const int tid = threadIdx.x;
    const int wave = tid >> 6, lane = tid & 63;
    const int wm = wave >> 1, wn = wave & 1;
    const int r0 = blockIdx.y * 128;
    const int c0 = blockIdx.x * 64;
    const int l15 = lane & 15, q = lane >> 4;

    // ---- LN pre-pass: 8 threads/row, 4 passes of 32 rows ----
    const int lane8 = tid & 7;         // channel group: ch = lane8*16 .. +15
    const int rgrp  = tid >> 3;        // 0..31
    float4 g4[4], b4[4];
    #pragma unroll
    for (int j = 0; j < 4; ++j) {
        g4[j] = *(const float4*)(lng + lane8 * 16 + j * 4);
        b4[j] = *(const float4*)(lnb + lane8 * 16 + j * 4);
    }
    #pragma unroll
    for (int p = 0; p < 4; ++p) {
        const int row = p * 32 + rgrp;
        int gr = r0 + row; gr = gr < Nr ? gr : Nr - 1;
        float4 v[4];
        #pragma unroll
        for (int j = 0; j < 4; ++j)
            v[j] = *(const float4*)(X + (size_t)gr * 128 + lane8 * 16 + j * 4);
        float s = 0.f, s2 = 0.f;
        #pragma unroll
        for (int j = 0; j < 4; ++j) {
            s  += v[j].x + v[j].y + v[j].z + v[j].w;
            s2 += v[j].x * v[j].x + v[j].y * v[j].y + v[j].z * v[j].z + v[j].w * v[j].w;
        }
        #pragma unroll
        for (int m = 1; m <= 4; m <<= 1) {
            s  += __shfl_xor(s,  m, 64);
            s2 += __shfl_xor(s2, m, 64);
        }
        const float mean = s * (1.0f / 128.0f);
        const float var  = s2 * (1.0f / 128.0f) - mean * mean;
        const float rs = rsqrtf(var + 1e-5f);
        uint pk[8];
        #pragma unroll
        for (int j = 0; j < 4; ++j) {
            float ox = (v[j].x - mean) * rs * g4[j].x + b4[j].x;
            float oy = (v[j].y - mean) * rs * g4[j].y + b4[j].y;
            float oz = (v[j].z - mean) * rs * g4[j].z + b4[j].z;
            float ow = (v[j].w - mean) * rs * g4[j].w + b4[j].w;
            pk[j * 2]     = f2bf(ox) | (f2bf(oy) << 16);
            pk[j * 2 + 1] = f2bf(oz) | (f2bf(ow) << 16);
        }
        uint4 w0 = {pk[0], pk[1], pk[2], pk[3]};
        uint4 w1 = {pk[4], pk[5], pk[6], pk[7]};
        *(uint4*)(As + row * 136 + lane8 * 16)     = w0;
        *(uint4*)(As + row * 136 + lane8 * 16 + 8) = w1;
    }

    // ---- stage B full-K: 64 rows x 128 ush, 4 passes ----
    #pragma unroll
    for (int p = 0; p < 4; ++p) {
        int flat = p * 256 + tid;
        int row = flat >> 4, c8 = flat & 15;
        uint4 v = *(const uint4*)(Bt + (size_t)(c0 + row) * 128 + c8 * 8);
        *(uint4*)(Bs + row * 136 + c8 * 8) = v;
    }
    __syncthreads();   // the only barrier

    f32x4 acc[4][2];
    #pragma unroll
    for (int t = 0; t < 4; ++t)
        #pragma unroll
        for (int u = 0; u < 2; ++u) {
            f32x4 z = {0.f, 0.f, 0.f, 0.f};
            acc[t][u] = z;
        }

    #pragma unroll
    for (int kh = 0; kh < 4; ++kh) {
        const int ko = kh * 32 + q * 8;
        bf16x8 a[4], b[2];
        #pragma unroll
        for (int t = 0; t < 4; ++t)
            a[t] = *(const bf16x8*)(As + (wm * 64 + t * 16 + l15) * 136 + ko);
        #pragma unroll
        for (int u = 0; u < 2; ++u)
            b[u] = *(const bf16x8*)(Bs + (wn * 32 + u * 16 + l15) * 136 + ko);
        #pragma unroll
        for (int t = 0; t < 4; ++t)
            #pragma unroll
            for (int u = 0; u < 2; ++u)
                acc[t][u] = __builtin_amdgcn_mfma_f32_16x16x32_bf16(
                    a[t], b[u], acc[t][u], 0, 0, 0);
    }

    // epilogue: C/D layout col=lane&15, row=(lane>>4)*4+reg
    #pragma unroll
    for (int t = 0; t < 4; ++t) {
        int grow = r0 + wm * 64 + t * 16 + q * 4;
        #pragma unroll
        for (int u = 0; u < 2; ++u) {
            int gcol = c0 + wn * 32 + u * 16 + l15;
            float bv = (gcol < bsplit) ? bias[gcol] : bias2[gcol - bsplit];
            #pragma unroll
            for (int i = 0; i < 4; ++i) {
                int r = grow + i;
                if (r >= Nr) continue;
                float v = acc[t][u][i] + bv;
                if (EPI == 1) v = gelu_tanh(v);
                Cout[(size_t)r * M + gcol] = (ushort)f2bf(v);
            }
        }
    }
}

// ---------------- bf16 MFMA GEMM (R4 config): A[Nr][K] @ Bt[M][K]^T -----------
// 128x64 tile, BK=64, 4 waves (2x2), LDS pad 72. Used for K=256/512.
// EPI: 2=bias+residual->fp32.
template<int EPI>
__global__ __launch_bounds__(256) void gemm_mfma(
    const ushort* __restrict__ A, const ushort* __restrict__ Bt,
    const float* __restrict__ bias, const float* __restrict__ R,
    void* __restrict__ Cout, int Nr, int K, int M)
{
    __shared__ ushort As[128 * 72];
    __shared__ ushort Bs[64 * 72];
    const int tid = threadIdx.x;
    const int wave = tid >> 6, lane = tid & 63;
    const int wm = wave >> 1, wn = wave & 1;
    const int r0 = blockIdx.y * 128;
    const int c0 = blockIdx.x * 64;
    const int l15 = lane & 15, q = lane >> 4;

    f32x4 acc[4][2];
    #pragma unroll
    for (int t = 0; t < 4; ++t)
        #pragma unroll
        for (int u = 0; u < 2; ++u) {
            f32x4 z = {0.f, 0.f, 0.f, 0.f};
            acc[t][u] = z;
        }

    for (int k0 = 0; k0 < K; k0 += 64) {
        #pragma unroll
        for (int p = 0; p < 4; ++p) {
            int flat = p * 256 + tid;
            int row = flat >> 3, c8 = flat & 7;
            int gr = r0 + row; gr = gr < Nr ? gr : Nr - 1;
            uint4 v = *(const uint4*)(A + (size_t)gr * K + k0 + c8 * 8);
            *(uint4*)(As + row * 72 + c8 * 8) = v;
        }
        #pragma unroll
        for (int p = 0; p < 2; ++p) {
            int flat = p * 256 + tid;
            int row = flat >> 3, c8 = flat & 7;
            uint4 v = *(const uint4*)(Bt + (size_t)(c0 + row) * K + k0 + c8 * 8);
            *(uint4*)(Bs + row * 72 + c8 * 8) = v;
        }
        __syncthreads();
        #pragma unroll
        for (int kh = 0; kh < 2; ++kh) {
            const int ko = kh * 32 + q * 8;
            bf16x8 a[4], b[2];
            #pragma unroll
            for (int t = 0; t < 4; ++t)
                a[t] = *(const bf16x8*)(As + (wm * 64 + t * 16 + l15) * 72 + ko);
            #pragma unroll
            for (int u = 0; u < 2; ++u)
                b[u] = *(const bf16x8*)(Bs + (wn * 32 + u * 16 + l15) * 72 + ko);
            #pragma unroll
            for (int t = 0; t < 4; ++t)
                #pragma unroll
                for (int u = 0; u < 2; ++u)
                    acc[t][u] = __builtin_amdgcn_mfma_f32_16x16x32_bf16(
                        a[t], b[u], acc[t][u], 0, 0, 0);
        }
        __syncthreads();
    }

    #pragma unroll
    for (int t = 0; t < 4; ++t) {
        int grow = r0 + wm * 64 + t * 16 + q * 4;
        #pragma unroll
        for (int u = 0; u < 2; ++u) {
            int gcol = c0 + wn * 32 + u * 16 + l15;
            float bv = bias[gcol];
            #pragma unroll
            for (int i = 0; i < 4; ++i) {
                int r = grow + i;
                if (r >= Nr) continue;
                float v = acc[t][u][i] + bv;
                if (EPI == 2) {
                    v += R[(size_t)r * M + gcol];
                    ((float*)Cout)[(size_t)r * M + gcol] = v;
                } else {
                    ((ushort*)Cout)[(size_t)r * M + gcol] = (ushort)f2bf(v);
                }
            }
        }
    }
}

// ---------------- scan-free CSR: atomic bucket fill ---------------------------
__global__ __launch_bounds__(256) void bucket_kernel(
    const int* __restrict__ src, const int* __restrict__ dst,
    int* __restrict__ deg, int* __restrict__ esrc, int E)
{
    int e = blockIdx.x * 256 + threadIdx.x;
    if (e >= E) return;
    int d = dst[e];
    int pos = atomicAdd(&deg[d], 1);
    if (pos < CAP) esrc[(size_t)d * CAP + pos] = src[e];
}

// -------- GAT aggregation v4: register edge indices + depth-2 prefetch --------
__global__ __launch_bounds__(256) void gat_gather(
    const int* __restrict__ deg, const int* __restrict__ esrc,
    const ushort* __restrict__ xlr, const float* __restrict__ att,
    const float* __restrict__ gat_b, ushort* __restrict__ agg, int N)
{
    int node = blockIdx.x * 4 + (threadIdx.x >> 6);
    if (node >= N) return;
    const int lane = threadIdx.x & 63;
    const int half = lane >> 5, sl = lane & 31;
    const int c = sl * 8;

    const uint4 rq = *(const uint4*)(xlr + (size_t)node * 512 + 256 + c);
    const f32x2 r01 = bfpair(rq.x), r23 = bfpair(rq.y);
    const f32x2 r45 = bfpair(rq.z), r67 = bfpair(rq.w);
    const float4 af0 = *(const float4*)(att + c);
    const float4 af1 = *(const float4*)(att + c + 4);
    const f32x2 a01 = {af0.x, af0.y}, a23 = {af0.z, af0.w};
    const f32x2 a45 = {af1.x, af1.y}, a67 = {af1.z, af1.w};

    int dc = deg[node]; dc = dc < CAP ? dc : CAP;
    const int base = node * CAP;
    f32x2 acc01 = {0.f, 0.f}, acc23 = {0.f, 0.f}, acc45 = {0.f, 0.f}, acc67 = {0.f, 0.f};
    float den = 0.f;

    if (dc > 0) {
        int slc = sl < dc ? sl : dc - 1;
        const int idxreg = esrc[base + slc];

        auto getsrc = [&](int e) -> int {
            int idx = e < dc ? e : dc - 1;
            int s = __shfl(idxreg, (lane & 32) | (idx & 31), 64);
            if (idx >= 32) s = esrc[base + idx];
            return s;
        };

        const int iters = (dc + 1) >> 1;
        int e0 = half;
        int s0 = getsrc(e0);
        uint4 lq0 = *(const uint4*)(xlr + (size_t)s0 * 512 + c);
        int e1 = e0 + 2;
        int s1 = getsrc(e1);
        uint4 lq1 = *(const uint4*)(xlr + (size_t)s1 * 512 + c);

        for (int it = 0; it < iters; ++it) {
            const int e2 = e0 + 4;
            const int s2 = getsrc(e2);
            const uint4 lq2 = *(const uint4*)(xlr + (size_t)s2 * 512 + c);

            const f32x2 l01 = bfpair(lq0.x), l23 = bfpair(lq0.y);
            const f32x2 l45 = bfpair(lq0.z), l67 = bfpair(lq0.w);
            f32x2 t, p2;
            t = l01 + r01; p2  = a01 * __builtin_elementwise_max(t, 0.2f * t);
            t = l23 + r23; p2 += a23 * __builtin_elementwise_max(t, 0.2f * t);
            t = l45 + r45; p2 += a45 * __builtin_elementwise_max(t, 0.2f * t);
            t = l67 + r67; p2 += a67 * __builtin_elementwise_max(t, 0.2f * t);
            float p = p2.x + p2.y;
            p += __shfl_xor(p, 1, 64);
            p += __shfl_xor(p, 2, 64);
            p += __shfl_xor(p, 4, 64);
            p += __shfl_xor(p, 8, 64);
            const float ex = (e0 < dc) ? __expf(p) : 0.f;   // O(1) scores: no max-sub
            acc01 += ex * l01; acc23 += ex * l23; acc45 += ex * l45; acc67 += ex * l67;
            den += ex;
            e0 = e1; lq0 = lq1;
            e1 = e2; lq1 = lq2;
        }
    }
    acc01.x += __shfl_xor(acc01.x, 32, 64); acc01.y += __shfl_xor(acc01.y, 32, 64);
    acc23.x += __shfl_xor(acc23.x, 32, 64); acc23.y += __shfl_xor(acc23.y, 32, 64);
    acc45.x += __shfl_xor(acc45.x, 32, 64); acc45.y += __shfl_xor(acc45.y, 32, 64);
    acc67.x += __shfl_xor(acc67.x, 32, 64); acc67.y += __shfl_xor(acc67.y, 32, 64);
    den     += __shfl_xor(den,     32, 64);

    if (half == 0) {
        const float inv = 1.0f / (den + 1e-16f);
        const float4 g0 = *(const float4*)(gat_b + c);
        const float4 g1 = *(const float4*)(gat_b + c + 4);
        uint4 o;
        o.x = f2bf(acc01.x * inv + g0.x) | (f2bf(acc01.y * inv + g0.y) << 16);
        o.y = f2bf(acc23.x * inv + g0.z) | (f2bf(acc23.y * inv + g0.w) << 16);
        o.z = f2bf(acc45.x * inv + g1.x) | (f2bf(acc45.y * inv + g1.y) << 16);
        o.w = f2bf(acc67.x * inv + g1.z) | (f2bf(acc67.y * inv + g1.w) << 16);
        *(uint4*)(agg + (size_t)node * HD + c) = o;
    }
}

extern "C" void kernel_launch(void* const* d_in, const int* in_sizes, int n_in,
                              void* d_out, int out_size, void* d_ws, size_t ws_size,
                              hipStream_t stream) {
    const float* x_in   = (const float*)d_in[0];
    const int*   eidx   = (const int*)d_in[1];
    const float* ln1_g  = (const float*)d_in[2];
    const float* ln1_b  = (const float*)d_in[3];
    const float* Wl     = (const float*)d_in[4];
    const float* bl     = (const float*)d_in[5];
    const float* Wr     = (const float*)d_in[6];
    const float* br     = (const float*)d_in[7];
    const float* att    = (const float*)d_in[8];
    const float* gat_b  = (const float*)d_in[9];
    const float* projW  = (const float*)d_in[10];
    const float* projb  = (const float*)d_in[11];
    const float* ln2_g  = (const float*)d_in[12];
    const float* ln2_b  = (const float*)d_in[13];
    const float* W1     = (const float*)d_in[14];
    const float* b1     = (const float*)d_in[15];
    const float* W2     = (const float*)d_in[16];
    const float* b2     = (const float*)d_in[17];

    const int N = N_NODES;
    const int E = in_sizes[1] / 2;
    const int* src = eidx;
    const int* dst = eidx + E;

    // workspace layout
    char* ws = (char*)d_ws;
    size_t off = 0;
    ushort* xlr  = (ushort*)(ws + off); off += (size_t)N * 512 * 2;   // 51.2 MB
    ushort* agg  = (ushort*)(ws + off); off += (size_t)N * HD * 2;    // 25.6 MB
    ushort* WlWr_t = (ushort*)(ws + off); off += (size_t)DEPTH * 512 * 128 * 2;
    ushort* pW_t   = (ushort*)(ws + off); off += (size_t)DEPTH * 128 * 256 * 2;
    ushort* W1_t   = (ushort*)(ws + off); off += (size_t)DEPTH * 512 * 128 * 2;
    ushort* W2_t   = (ushort*)(ws + off); off += (size_t)DEPTH * 128 * 512 * 2;
    int* deg     = (int*)(ws + off);    off += (size_t)N * 4;
    int* esrc    = (int*)(ws + off);    off += (size_t)N * CAP * 4;   // 19.2 MB
    ushort* mid  = xlr;   // FFN intermediate [N,512] bf16 aliases xlr

    float* x = (float*)d_out;

    const int nodeBlocks = (N + 3) / 4;
    const dim3 blk(256);
    const int gy = (N + 127) / 128;

    wconv_all<<<(458752 + 255) / 256, blk, 0, stream>>>(
        Wl, Wr, projW, W1, W2, WlWr_t, pW_t, W1_t, W2_t);

    hipMemsetAsync(deg, 0, (size_t)N * 4, stream);
    bucket_kernel<<<(E + 255) / 256, blk, 0, stream>>>(src, dst, deg, esrc, E);

    for (int L = 0; L < DEPTH; ++L) {
        const float* bl_i   = bl + (size_t)L * HD;
        const float* br_i   = br + (size_t)L * HD;
        const float* att_i  = att + (size_t)L * HD;
        const float* gatb_i = gat_b + (size_t)L * HD;
        const float* pb_i   = projb + (size_t)L * DIM;
        const float* b1_i   = b1 + (size_t)L * MLP;
        const float* b2_i   = b2 + (size_t)L * DIM;
        const float* xin_L  = (L == 0) ? x_in : x;   // layer-0 reads input directly

        // xlr = LN1(x) @ [Wl|Wr] + [bl|br]   (LN fused, bf16 out, M=512)
        gemm_ln<0><<<dim3(8, gy), blk, 0, stream>>>(
            xin_L, WlWr_t + (size_t)L * 512 * 128, ln1_g + L * DIM, ln1_b + L * DIM,
            bl_i, br_i, HD, xlr, N, 512);
        // agg = segment-softmax aggregate
        gat_gather<<<nodeBlocks, blk, 0, stream>>>(deg, esrc, xlr, att_i, gatb_i, agg, N);
        // x = xin + agg@projW + projb  (fp32 out to d_out)
        gemm_mfma<2><<<dim3(2, gy), blk, 0, stream>>>(
            agg, pW_t + (size_t)L * 128 * 256, pb_i, xin_L, x, N, 256, 128);
        // mid = gelu(LN2(x)@W1 + b1)   (LN fused, bf16 out, M=512)
        gemm_ln<1><<<dim3(8, gy), blk, 0, stream>>>(
            x, W1_t + (size_t)L * 512 * 128, ln2_g + L * DIM, ln2_b + L * DIM,
            b1_i, b1_i, 1 << 30, mid, N, 512);
        // x = x + mid@W2 + b2  (K=512)
        gemm_mfma<2><<<dim3(2, gy), blk, 0, stream>>>(
            mid, W2_t + (size_t)L * 128 * 512, b2_i, x, x, N, 512, 128);
    }
}

// Round 13
// 568.339 us; speedup vs baseline: 1.0390x; 1.0390x over previous
//
#include <hip/hip_runtime.h>

typedef unsigned int uint;
typedef unsigned short ushort;
typedef __attribute__((ext_vector_type(4))) float f32x4;
typedef __attribute__((ext_vector_type(2))) float f32x2;
typedef __attribute__((ext_vector_type(8))) short bf16x8;

#define N_NODES 50000
#define DIM 128
#define HEADS 2
#define HD 256      // HEADS*DIM
#define MLP 512
#define DEPTH 2
#define CAP 96      // max in-degree bucket capacity (Poisson(16): P(>96) ~ 1e-40)

// ---- bf16 helpers (manual, RNE) ----
__device__ __forceinline__ uint f2bf(float f) {
    uint u = __float_as_uint(f);
    return (u + 0x7FFFu + ((u >> 16) & 1u)) >> 16;   // round-nearest-even
}
__device__ __forceinline__ f32x2 bfpair(uint u) {
    f32x2 r;
    r.x = __uint_as_float(u << 16);
    r.y = __uint_as_float(u & 0xFFFF0000u);
    return r;
}

__device__ __forceinline__ float gelu_tanh(float x) {
    float t = 0.7978845608028654f * (x + 0.044715f * x * x * x);
    float e = __expf(2.0f * t);
    float th = 1.0f - 2.0f / (e + 1.0f);   // tanh(t), overflow-safe
    return 0.5f * x * (1.0f + th);
}

// ---------------- LayerNorm (LN1): one wave per node, bf16 output -------------
__global__ __launch_bounds__(256) void ln_kernel(
    const float* __restrict__ x, const float* __restrict__ g,
    const float* __restrict__ b, ushort* __restrict__ out, int N)
{
    int node = blockIdx.x * 4 + (threadIdx.x >> 6);
    if (node >= N) return;
    int lane = threadIdx.x & 63;
    const float2 v = *(const float2*)(x + (size_t)node * DIM + lane * 2);
    float s = v.x + v.y;
    float s2 = v.x * v.x + v.y * v.y;
    #pragma unroll
    for (int m = 1; m <= 32; m <<= 1) {
        s  += __shfl_xor(s,  m, 64);
        s2 += __shfl_xor(s2, m, 64);
    }
    float mean = s * (1.0f / 128.0f);
    float var  = s2 * (1.0f / 128.0f) - mean * mean;
    float rs = rsqrtf(var + 1e-5f);
    float ox = (v.x - mean) * rs * g[lane * 2]     + b[lane * 2];
    float oy = (v.y - mean) * rs * g[lane * 2 + 1] + b[lane * 2 + 1];
    uint pk = f2bf(ox) | (f2bf(oy) << 16);
    *(uint*)(out + (size_t)node * DIM + lane * 2) = pk;
}

// ------- fused prep: weight convert+transpose (bf16) + CSR bucket fill --------
// i < 458752: weight conversion; i >= 458752: edge bucket scatter.
__global__ __launch_bounds__(256) void prep_kernel(
    const float* __restrict__ Wl, const float* __restrict__ Wr,
    const float* __restrict__ pW, const float* __restrict__ W1,
    const float* __restrict__ W2, ushort* __restrict__ WlWr_t,
    ushort* __restrict__ pW_t, ushort* __restrict__ W1_t,
    ushort* __restrict__ W2_t,
    const int* __restrict__ src, const int* __restrict__ dst,
    int* __restrict__ deg, int* __restrict__ esrc, int E)
{
    int i = blockIdx.x * 256 + threadIdx.x;
    if (i < 65536) {                       // Wl [D][128][256] -> [D][512][128] rows 0..255
        int l = i >> 15, rem = i & 32767;
        int k = rem >> 8, m = rem & 255;
        WlWr_t[l * 65536 + m * 128 + k] = (ushort)f2bf(Wl[i]);
    } else if (i < 131072) {               // Wr -> rows 256..511
        int j = i - 65536;
        int l = j >> 15, rem = j & 32767;
        int k = rem >> 8, m = rem & 255;
        WlWr_t[l * 65536 + (m + 256) * 128 + k] = (ushort)f2bf(Wr[j]);
    } else if (i < 196608) {               // proj [D][256][128] -> [D][128][256]
        int j = i - 131072;
        int l = j >> 15, rem = j & 32767;
        int k = rem >> 7, m = rem & 127;
        pW_t[l * 32768 + m * 256 + k] = (ushort)f2bf(pW[j]);
    } else if (i < 327680) {               // W1 [D][128][512] -> [D][512][128]
        int j = i - 196608;
        int l = j >> 16, rem = j & 65535;
        int k = rem >> 9, m = rem & 511;
        W1_t[l * 65536 + m * 128 + k] = (ushort)f2bf(W1[j]);
    } else if (i < 458752) {               // W2 [D][512][128] -> [D][128][512]
        int j = i - 327680;
        int l = j >> 16, rem = j & 65535;
        int k = rem >> 7, m = rem & 127;
        W2_t[l * 65536 + m * 512 + k] = (ushort)f2bf(W2[j]);
    } else {                               // edge bucket fill
        int e = i - 458752;
        if (e < E) {
            int d = dst[e];
            int pos = atomicAdd(&deg[d], 1);
            if (pos < CAP) esrc[(size_t)d * CAP + pos] = src[e];
        }
    }
}

// ---------------- bf16 MFMA GEMM (R4 config): A[Nr][K] @ Bt[M][K]^T -----------
// 128x64 tile, BK=64, 4 waves (2x2), LDS pad 72 (2-way bank alias = free).
// EPI: 0=bias->bf16, 1=bias+gelu->bf16, 2=bias+residual->fp32.
template<int EPI>
__global__ __launch_bounds__(256) void gemm_mfma(
    const ushort* __restrict__ A, const ushort* __restrict__ Bt,
    const float* __restrict__ bias, const float* __restrict__ bias2, int bsplit,
    const float* __restrict__ R, void* __restrict__ Cout, int Nr, int K, int M)
{
    __shared__ ushort As[128 * 72];
    __shared__ ushort Bs[64 * 72];
    const int tid = threadIdx.x;
    const int wave = tid >> 6, lane = tid & 63;
    const int wm = wave >> 1, wn = wave & 1;
    const int r0 = blockIdx.y * 128;
    const int c0 = blockIdx.x * 64;
    const int l15 = lane & 15, q = lane >> 4;

    f32x4 acc[4][2];
    #pragma unroll
    for (int t = 0; t < 4; ++t)
        #pragma unroll
        for (int u = 0; u < 2; ++u) {
            f32x4 z = {0.f, 0.f, 0.f, 0.f};
            acc[t][u] = z;
        }

    for (int k0 = 0; k0 < K; k0 += 64) {
        #pragma unroll
        for (int p = 0; p < 4; ++p) {
            int flat = p * 256 + tid;
            int row = flat >> 3, c8 = flat & 7;
            int gr = r0 + row; gr = gr < Nr ? gr : Nr - 1;
            uint4 v = *(const uint4*)(A + (size_t)gr * K + k0 + c8 * 8);
            *(uint4*)(As + row * 72 + c8 * 8) = v;
        }
        #pragma unroll
        for (int p = 0; p < 2; ++p) {
            int flat = p * 256 + tid;
            int row = flat >> 3, c8 = flat & 7;
            uint4 v = *(const uint4*)(Bt + (size_t)(c0 + row) * K + k0 + c8 * 8);
            *(uint4*)(Bs + row * 72 + c8 * 8) = v;
        }
        __syncthreads();
        #pragma unroll
        for (int kh = 0; kh < 2; ++kh) {
            const int ko = kh * 32 + q * 8;
            bf16x8 a[4], b[2];
            #pragma unroll
            for (int t = 0; t < 4; ++t)
                a[t] = *(const bf16x8*)(As + (wm * 64 + t * 16 + l15) * 72 + ko);
            #pragma unroll
            for (int u = 0; u < 2; ++u)
                b[u] = *(const bf16x8*)(Bs + (wn * 32 + u * 16 + l15) * 72 + ko);
            #pragma unroll
            for (int t = 0; t < 4; ++t)
                #pragma unroll
                for (int u = 0; u < 2; ++u)
                    acc[t][u] = __builtin_amdgcn_mfma_f32_16x16x32_bf16(
                        a[t], b[u], acc[t][u], 0, 0, 0);
        }
        __syncthreads();
    }

    // epilogue: C/D layout col=lane&15, row=(lane>>4)*4+reg
    #pragma unroll
    for (int t = 0; t < 4; ++t) {
        int grow = r0 + wm * 64 + t * 16 + q * 4;
        #pragma unroll
        for (int u = 0; u < 2; ++u) {
            int gcol = c0 + wn * 32 + u * 16 + l15;
            float bv = (gcol < bsplit) ? bias[gcol] : bias2[gcol - bsplit];
            #pragma unroll
            for (int i = 0; i < 4; ++i) {
                int r = grow + i;
                if (r >= Nr) continue;
                float v = acc[t][u][i] + bv;
                if (EPI == 1) v = gelu_tanh(v);
                if (EPI == 2) {
                    v += R[(size_t)r * M + gcol];
                    ((float*)Cout)[(size_t)r * M + gcol] = v;
                } else {
                    ((ushort*)Cout)[(size_t)r * M + gcol] = (ushort)f2bf(v);
                }
            }
        }
    }
}

// -------- proj GEMM + residual + fused LN2 epilogue ---------------------------
// x = xin + agg@pWt^T + pb  (fp32 out), h = bf16(LN2(x)).
// Tile: 64 rows x 128 cols (full M) per block so rows are complete for LN.
// Waves 2x2: wm=row half (32 rows), wn=col half (64 cols). LDS 28.7 KB.
__global__ __launch_bounds__(256) void proj_ln(
    const ushort* __restrict__ A, const ushort* __restrict__ Bt,
    const float* __restrict__ pb, const float* __restrict__ xin,
    const float* __restrict__ lng, const float* __restrict__ lnb,
    float* __restrict__ x, ushort* __restrict__ h, int Nr)
{
    __shared__ ushort As[64 * 72];     // 9.2 KB
    __shared__ ushort Bs[128 * 72];    // 18.4 KB
    __shared__ float red[64][4];       // 1 KB: [row][wn*2 + {s,s2}]
    const int tid = threadIdx.x;
    const int wave = tid >> 6, lane = tid & 63;
    const int wm = wave >> 1, wn = wave & 1;
    const int r0 = blockIdx.y * 64;
    const int l15 = lane & 15, q = lane >> 4;
    const int K = 256;

    f32x4 acc[2][4];
    #pragma unroll
    for (int t = 0; t < 2; ++t)
        #pragma unroll
        for (int u = 0; u < 4; ++u) {
            f32x4 z = {0.f, 0.f, 0.f, 0.f};
            acc[t][u] = z;
        }

    for (int k0 = 0; k0 < K; k0 += 64) {
        // stage A: 64 rows x 64 (2 passes)
        #pragma unroll
        for (int p = 0; p < 2; ++p) {
            int flat = p * 256 + tid;
            int row = flat >> 3, c8 = flat & 7;
            int gr = r0 + row; gr = gr < Nr ? gr : Nr - 1;
            uint4 v = *(const uint4*)(A + (size_t)gr * K + k0 + c8 * 8);
            *(uint4*)(As + row * 72 + c8 * 8) = v;
        }
        // stage B: 128 rows (output cols) x 64 (4 passes)
        #pragma unroll
        for (int p = 0; p < 4; ++p) {
            int flat = p * 256 + tid;
            int row = flat >> 3, c8 = flat & 7;
            uint4 v = *(const uint4*)(Bt + (size_t)row * K + k0 + c8 * 8);
            *(uint4*)(Bs + row * 72 + c8 * 8) = v;
        }
        __syncthreads();
        #pragma unroll
        for (int kh = 0; kh < 2; ++kh) {
            const int ko = kh * 32 + q * 8;
            bf16x8 a[2], b[4];
            #pragma unroll
            for (int t = 0; t < 2; ++t)
                a[t] = *(const bf16x8*)(As + (wm * 32 + t * 16 + l15) * 72 + ko);
            #pragma unroll
            for (int u = 0; u < 4; ++u)
                b[u] = *(const bf16x8*)(Bs + (wn * 64 + u * 16 + l15) * 72 + ko);
            #pragma unroll
            for (int t = 0; t < 2; ++t)
                #pragma unroll
                for (int u = 0; u < 4; ++u)
                    acc[t][u] = __builtin_amdgcn_mfma_f32_16x16x32_bf16(
                        a[t], b[u], acc[t][u], 0, 0, 0);
        }
        __syncthreads();
    }

    // epilogue: v = acc + pb + xin ; store x ; LN over each full row -> h
    float vreg[2][4][4];
    float s[2][4], s2[2][4];
    #pragma unroll
    for (int t = 0; t < 2; ++t)
        #pragma unroll
        for (int i = 0; i < 4; ++i) { s[t][i] = 0.f; s2[t][i] = 0.f; }

    #pragma unroll
    for (int t = 0; t < 2; ++t) {
        #pragma unroll
        for (int u = 0; u < 4; ++u) {
            int gcol = wn * 64 + u * 16 + l15;
            float bv = pb[gcol];
            #pragma unroll
            for (int i = 0; i < 4; ++i) {
                int r = r0 + wm * 32 + t * 16 + q * 4 + i;
                int rc = r < Nr ? r : Nr - 1;
                float v = acc[t][u][i] + bv + xin[(size_t)rc * DIM + gcol];
                if (r < Nr) x[(size_t)r * DIM + gcol] = v;
                vreg[t][u][i] = v;
                s[t][i]  += v;
                s2[t][i] += v * v;
            }
        }
    }
    // reduce across the 16-lane group (same q): row sums over this wave's 64 cols
    #pragma unroll
    for (int t = 0; t < 2; ++t)
        #pragma unroll
        for (int i = 0; i < 4; ++i) {
            #pragma unroll
            for (int m = 1; m <= 8; m <<= 1) {
                s[t][i]  += __shfl_xor(s[t][i],  m, 64);
                s2[t][i] += __shfl_xor(s2[t][i], m, 64);
            }
        }
    if (l15 == 0) {
        #pragma unroll
        for (int t = 0; t < 2; ++t)
            #pragma unroll
            for (int i = 0; i < 4; ++i) {
                int row = wm * 32 + t * 16 + q * 4 + i;
                red[row][wn * 2]     = s[t][i];
                red[row][wn * 2 + 1] = s2[t][i];
            }
    }
    __syncthreads();
    #pragma unroll
    for (int t = 0; t < 2; ++t) {
        #pragma unroll
        for (int i = 0; i < 4; ++i) {
            int row = wm * 32 + t * 16 + q * 4 + i;
            float S  = red[row][0] + red[row][2];
            float S2 = red[row][1] + red[row][3];
            float mean = S * (1.0f / 128.0f);
            float var  = S2 * (1.0f / 128.0f) - mean * mean;
            float rs = rsqrtf(var + 1e-5f);
            int r = r0 + row;
            if (r >= Nr) continue;
            #pragma unroll
            for (int u = 0; u < 4; ++u) {
                int gcol = wn * 64 + u * 16 + l15;
                float hv = (vreg[t][u][i] - mean) * rs * lng[gcol] + lnb[gcol];
                h[(size_t)r * DIM + gcol] = (ushort)f2bf(hv);
            }
        }
    }
}

// -------- GAT aggregation v4: register edge indices + depth-2 prefetch --------
__global__ __launch_bounds__(256) void gat_gather(
    const int* __restrict__ deg, const int* __restrict__ esrc,
    const ushort* __restrict__ xlr, const float* __restrict__ att,
    const float* __restrict__ gat_b, ushort* __restrict__ agg, int N)
{
    int node = blockIdx.x * 4 + (threadIdx.x >> 6);
    if (node >= N) return;
    const int lane = threadIdx.x & 63;
    const int half = lane >> 5, sl = lane & 31;
    const int c = sl * 8;

    const uint4 rq = *(const uint4*)(xlr + (size_t)node * 512 + 256 + c);
    const f32x2 r01 = bfpair(rq.x), r23 = bfpair(rq.y);
    const f32x2 r45 = bfpair(rq.z), r67 = bfpair(rq.w);
    const float4 af0 = *(const float4*)(att + c);
    const float4 af1 = *(const float4*)(att + c + 4);
    const f32x2 a01 = {af0.x, af0.y}, a23 = {af0.z, af0.w};
    const f32x2 a45 = {af1.x, af1.y}, a67 = {af1.z, af1.w};

    int dc = deg[node]; dc = dc < CAP ? dc : CAP;
    const int base = node * CAP;
    f32x2 acc01 = {0.f, 0.f}, acc23 = {0.f, 0.f}, acc45 = {0.f, 0.f}, acc67 = {0.f, 0.f};
    float den = 0.f;

    if (dc > 0) {
        int slc = sl < dc ? sl : dc - 1;
        const int idxreg = esrc[base + slc];

        auto getsrc = [&](int e) -> int {
            int idx = e < dc ? e : dc - 1;
            int s = __shfl(idxreg, (lane & 32) | (idx & 31), 64);
            if (idx >= 32) s = esrc[base + idx];
            return s;
        };

        const int iters = (dc + 1) >> 1;
        int e0 = half;
        int s0 = getsrc(e0);
        uint4 lq0 = *(const uint4*)(xlr + (size_t)s0 * 512 + c);
        int e1 = e0 + 2;
        int s1 = getsrc(e1);
        uint4 lq1 = *(const uint4*)(xlr + (size_t)s1 * 512 + c);

        for (int it = 0; it < iters; ++it) {
            const int e2 = e0 + 4;
            const int s2 = getsrc(e2);
            const uint4 lq2 = *(const uint4*)(xlr + (size_t)s2 * 512 + c);

            const f32x2 l01 = bfpair(lq0.x), l23 = bfpair(lq0.y);
            const f32x2 l45 = bfpair(lq0.z), l67 = bfpair(lq0.w);
            f32x2 t, p2;
            t = l01 + r01; p2  = a01 * __builtin_elementwise_max(t, 0.2f * t);
            t = l23 + r23; p2 += a23 * __builtin_elementwise_max(t, 0.2f * t);
            t = l45 + r45; p2 += a45 * __builtin_elementwise_max(t, 0.2f * t);
            t = l67 + r67; p2 += a67 * __builtin_elementwise_max(t, 0.2f * t);
            float p = p2.x + p2.y;
            p += __shfl_xor(p, 1, 64);
            p += __shfl_xor(p, 2, 64);
            p += __shfl_xor(p, 4, 64);
            p += __shfl_xor(p, 8, 64);
            const float ex = (e0 < dc) ? __expf(p) : 0.f;   // O(1) scores: no max-sub
            acc01 += ex * l01; acc23 += ex * l23; acc45 += ex * l45; acc67 += ex * l67;
            den += ex;
            e0 = e1; lq0 = lq1;
            e1 = e2; lq1 = lq2;
        }
    }
    acc01.x += __shfl_xor(acc01.x, 32, 64); acc01.y += __shfl_xor(acc01.y, 32, 64);
    acc23.x += __shfl_xor(acc23.x, 32, 64); acc23.y += __shfl_xor(acc23.y, 32, 64);
    acc45.x += __shfl_xor(acc45.x, 32, 64); acc45.y += __shfl_xor(acc45.y, 32, 64);
    acc67.x += __shfl_xor(acc67.x, 32, 64); acc67.y += __shfl_xor(acc67.y, 32, 64);
    den     += __shfl_xor(den,     32, 64);

    if (half == 0) {
        const float inv = 1.0f / (den + 1e-16f);
        const float4 g0 = *(const float4*)(gat_b + c);
        const float4 g1 = *(const float4*)(gat_b + c + 4);
        uint4 o;
        o.x = f2bf(acc01.x * inv + g0.x) | (f2bf(acc01.y * inv + g0.y) << 16);
        o.y = f2bf(acc23.x * inv + g0.z) | (f2bf(acc23.y * inv + g0.w) << 16);
        o.z = f2bf(acc45.x * inv + g1.x) | (f2bf(acc45.y * inv + g1.y) << 16);
        o.w = f2bf(acc67.x * inv + g1.z) | (f2bf(acc67.y * inv + g1.w) << 16);
        *(uint4*)(agg + (size_t)node * HD + c) = o;
    }
}

extern "C" void kernel_launch(void* const* d_in, const int* in_sizes, int n_in,
                              void* d_out, int out_size, void* d_ws, size_t ws_size,
                              hipStream_t stream) {
    const float* x_in   = (const float*)d_in[0];
    const int*   eidx   = (const int*)d_in[1];
    const float* ln1_g  = (const float*)d_in[2];
    const float* ln1_b  = (const float*)d_in[3];
    const float* Wl     = (const float*)d_in[4];
    const float* bl     = (const float*)d_in[5];
    const float* Wr     = (const float*)d_in[6];
    const float* br     = (const float*)d_in[7];
    const float* att    = (const float*)d_in[8];
    const float* gat_b  = (const float*)d_in[9];
    const float* projW  = (const float*)d_in[10];
    const float* projb  = (const float*)d_in[11];
    const float* ln2_g  = (const float*)d_in[12];
    const float* ln2_b  = (const float*)d_in[13];
    const float* W1     = (const float*)d_in[14];
    const float* b1     = (const float*)d_in[15];
    const float* W2     = (const float*)d_in[16];
    const float* b2     = (const float*)d_in[17];

    const int N = N_NODES;
    const int E = in_sizes[1] / 2;
    const int* src = eidx;
    const int* dst = eidx + E;

    // workspace layout
    char* ws = (char*)d_ws;
    size_t off = 0;
    ushort* xlr  = (ushort*)(ws + off); off += (size_t)N * 512 * 2;   // 51.2 MB
    ushort* agg  = (ushort*)(ws + off); off += (size_t)N * HD * 2;    // 25.6 MB
    ushort* h    = (ushort*)(ws + off); off += (size_t)N * DIM * 2;   // 12.8 MB
    ushort* WlWr_t = (ushort*)(ws + off); off += (size_t)DEPTH * 512 * 128 * 2;
    ushort* pW_t   = (ushort*)(ws + off); off += (size_t)DEPTH * 128 * 256 * 2;
    ushort* W1_t   = (ushort*)(ws + off); off += (size_t)DEPTH * 512 * 128 * 2;
    ushort* W2_t   = (ushort*)(ws + off); off += (size_t)DEPTH * 128 * 512 * 2;
    int* deg     = (int*)(ws + off);    off += (size_t)N * 4;
    int* esrc    = (int*)(ws + off);    off += (size_t)N * CAP * 4;   // 19.2 MB
    ushort* mid  = xlr;   // FFN intermediate [N,512] bf16 aliases xlr

    float* x = (float*)d_out;

    const int nodeBlocks = (N + 3) / 4;
    const dim3 blk(256);
    const int gy = (N + 127) / 128;
    const int gy64 = (N + 63) / 64;

    hipMemsetAsync(deg, 0, (size_t)N * 4, stream);
    {
        int total = 458752 + E;
        prep_kernel<<<(total + 255) / 256, blk, 0, stream>>>(
            Wl, Wr, projW, W1, W2, WlWr_t, pW_t, W1_t, W2_t,
            src, dst, deg, esrc, E);
    }

    for (int L = 0; L < DEPTH; ++L) {
        const float* bl_i   = bl + (size_t)L * HD;
        const float* br_i   = br + (size_t)L * HD;
        const float* att_i  = att + (size_t)L * HD;
        const float* gatb_i = gat_b + (size_t)L * HD;
        const float* pb_i   = projb + (size_t)L * DIM;
        const float* b1_i   = b1 + (size_t)L * MLP;
        const float* b2_i   = b2 + (size_t)L * DIM;
        const float* xin_L  = (L == 0) ? x_in : x;   // layer-0 reads input directly

        // h = bf16(LN1(x))
        ln_kernel<<<nodeBlocks, blk, 0, stream>>>(xin_L, ln1_g + L * DIM, ln1_b + L * DIM, h, N);
        // xlr = h @ [Wl|Wr] + [bl|br]  (bf16, M=512, K=128)
        gemm_mfma<0><<<dim3(8, gy), blk, 0, stream>>>(
            h, WlWr_t + (size_t)L * 512 * 128, bl_i, br_i, HD, nullptr, xlr, N, 128, 512);
        // agg = segment-softmax aggregate
        gat_gather<<<nodeBlocks, blk, 0, stream>>>(deg, esrc, xlr, att_i, gatb_i, agg, N);
        // x = xin + agg@projW + projb ; h = bf16(LN2(x))   (fused epilogue)
        proj_ln<<<dim3(1, gy64), blk, 0, stream>>>(
            agg, pW_t + (size_t)L * 128 * 256, pb_i, xin_L,
            ln2_g + L * DIM, ln2_b + L * DIM, x, h, N);
        // mid = gelu(h@W1 + b1)  (bf16, M=512, K=128)
        gemm_mfma<1><<<dim3(8, gy), blk, 0, stream>>>(
            h, W1_t + (size_t)L * 512 * 128, b1_i, b1_i, 1 << 30, nullptr, mid, N, 128, 512);
        // x = x + mid@W2 + b2  (K=512)
        gemm_mfma<2><<<dim3(2, gy), blk, 0, stream>>>(
            mid, W2_t + (size_t)L * 128 * 512, b2_i, b2_i, 1 << 30, x, x, N, 512, 128);
    }
}

// Round 14
// 563.275 us; speedup vs baseline: 1.0483x; 1.0090x over previous
//
#include <hip/hip_runtime.h>

typedef unsigned int uint;
typedef unsigned short ushort;
typedef __attribute__((ext_vector_type(4))) float f32x4;
typedef __attribute__((ext_vector_type(2))) float f32x2;
typedef __attribute__((ext_vector_type(8))) short bf16x8;

#define N_NODES 50000
#define DIM 128
#define HEADS 2
#define HD 256      // HEADS*DIM
#define MLP 512
#define DEPTH 2
#define CAP 96      // max in-degree bucket capacity (Poisson(16): P(>96) ~ 1e-40)

// ---- bf16 helpers (manual, RNE) ----
__device__ __forceinline__ uint f2bf(float f) {
    uint u = __float_as_uint(f);
    return (u + 0x7FFFu + ((u >> 16) & 1u)) >> 16;   // round-nearest-even
}
__device__ __forceinline__ f32x2 bfpair(uint u) {
    f32x2 r;
    r.x = __uint_as_float(u << 16);
    r.y = __uint_as_float(u & 0xFFFF0000u);
    return r;
}

__device__ __forceinline__ float gelu_tanh(float x) {
    float t = 0.7978845608028654f * (x + 0.044715f * x * x * x);
    float e = __expf(2.0f * t);
    float th = 1.0f - 2.0f / (e + 1.0f);   // tanh(t), overflow-safe
    return 0.5f * x * (1.0f + th);
}

// ---------------- LayerNorm: one wave per node, bf16 output -------------------
__global__ __launch_bounds__(256) void ln_kernel(
    const float* __restrict__ x, const float* __restrict__ g,
    const float* __restrict__ b, ushort* __restrict__ out, int N)
{
    int node = blockIdx.x * 4 + (threadIdx.x >> 6);
    if (node >= N) return;
    int lane = threadIdx.x & 63;
    const float2 v = *(const float2*)(x + (size_t)node * DIM + lane * 2);
    float s = v.x + v.y;
    float s2 = v.x * v.x + v.y * v.y;
    #pragma unroll
    for (int m = 1; m <= 32; m <<= 1) {
        s  += __shfl_xor(s,  m, 64);
        s2 += __shfl_xor(s2, m, 64);
    }
    float mean = s * (1.0f / 128.0f);
    float var  = s2 * (1.0f / 128.0f) - mean * mean;
    float rs = rsqrtf(var + 1e-5f);
    float ox = (v.x - mean) * rs * g[lane * 2]     + b[lane * 2];
    float oy = (v.y - mean) * rs * g[lane * 2 + 1] + b[lane * 2 + 1];
    uint pk = f2bf(ox) | (f2bf(oy) << 16);
    *(uint*)(out + (size_t)node * DIM + lane * 2) = pk;
}

// ------- fused prep: weight convert+transpose (bf16) + CSR bucket fill --------
__global__ __launch_bounds__(256) void prep_kernel(
    const float* __restrict__ Wl, const float* __restrict__ Wr,
    const float* __restrict__ pW, const float* __restrict__ W1,
    const float* __restrict__ W2, ushort* __restrict__ WlWr_t,
    ushort* __restrict__ pW_t, ushort* __restrict__ W1_t,
    ushort* __restrict__ W2_t,
    const int* __restrict__ src, const int* __restrict__ dst,
    int* __restrict__ deg, int* __restrict__ esrc, int E)
{
    int i = blockIdx.x * 256 + threadIdx.x;
    if (i < 65536) {                       // Wl [D][128][256] -> [D][512][128] rows 0..255
        int l = i >> 15, rem = i & 32767;
        int k = rem >> 8, m = rem & 255;
        WlWr_t[l * 65536 + m * 128 + k] = (ushort)f2bf(Wl[i]);
    } else if (i < 131072) {               // Wr -> rows 256..511
        int j = i - 65536;
        int l = j >> 15, rem = j & 32767;
        int k = rem >> 8, m = rem & 255;
        WlWr_t[l * 65536 + (m + 256) * 128 + k] = (ushort)f2bf(Wr[j]);
    } else if (i < 196608) {               // proj [D][256][128] -> [D][128][256]
        int j = i - 131072;
        int l = j >> 15, rem = j & 32767;
        int k = rem >> 7, m = rem & 127;
        pW_t[l * 32768 + m * 256 + k] = (ushort)f2bf(pW[j]);
    } else if (i < 327680) {               // W1 [D][128][512] -> [D][512][128]
        int j = i - 196608;
        int l = j >> 16, rem = j & 65535;
        int k = rem >> 9, m = rem & 511;
        W1_t[l * 65536 + m * 128 + k] = (ushort)f2bf(W1[j]);
    } else if (i < 458752) {               // W2 [D][512][128] -> [D][128][512]
        int j = i - 327680;
        int l = j >> 16, rem = j & 65535;
        int k = rem >> 7, m = rem & 127;
        W2_t[l * 65536 + m * 512 + k] = (ushort)f2bf(W2[j]);
    } else {                               // edge bucket fill
        int e = i - 458752;
        if (e < E) {
            int d = dst[e];
            int pos = atomicAdd(&deg[d], 1);
            if (pos < CAP) esrc[(size_t)d * CAP + pos] = src[e];
        }
    }
}

// ---------------- bf16 MFMA GEMM (R4 config): A[Nr][K] @ Bt[M][K]^T -----------
// 128x64 tile, BK=64, 4 waves (2x2), LDS pad 72 (2-way bank alias = free).
// EPI: 0=bias->bf16, 1=bias+gelu->bf16, 2=bias+residual->fp32.
template<int EPI>
__global__ __launch_bounds__(256) void gemm_mfma(
    const ushort* __restrict__ A, const ushort* __restrict__ Bt,
    const float* __restrict__ bias, const float* __restrict__ bias2, int bsplit,
    const float* __restrict__ R, void* __restrict__ Cout, int Nr, int K, int M)
{
    __shared__ ushort As[128 * 72];
    __shared__ ushort Bs[64 * 72];
    const int tid = threadIdx.x;
    const int wave = tid >> 6, lane = tid & 63;
    const int wm = wave >> 1, wn = wave & 1;
    const int r0 = blockIdx.y * 128;
    const int c0 = blockIdx.x * 64;
    const int l15 = lane & 15, q = lane >> 4;

    f32x4 acc[4][2];
    #pragma unroll
    for (int t = 0; t < 4; ++t)
        #pragma unroll
        for (int u = 0; u < 2; ++u) {
            f32x4 z = {0.f, 0.f, 0.f, 0.f};
            acc[t][u] = z;
        }

    for (int k0 = 0; k0 < K; k0 += 64) {
        #pragma unroll
        for (int p = 0; p < 4; ++p) {
            int flat = p * 256 + tid;
            int row = flat >> 3, c8 = flat & 7;
            int gr = r0 + row; gr = gr < Nr ? gr : Nr - 1;
            uint4 v = *(const uint4*)(A + (size_t)gr * K + k0 + c8 * 8);
            *(uint4*)(As + row * 72 + c8 * 8) = v;
        }
        #pragma unroll
        for (int p = 0; p < 2; ++p) {
            int flat = p * 256 + tid;
            int row = flat >> 3, c8 = flat & 7;
            uint4 v = *(const uint4*)(Bt + (size_t)(c0 + row) * K + k0 + c8 * 8);
            *(uint4*)(Bs + row * 72 + c8 * 8) = v;
        }
        __syncthreads();
        #pragma unroll
        for (int kh = 0; kh < 2; ++kh) {
            const int ko = kh * 32 + q * 8;
            bf16x8 a[4], b[2];
            #pragma unroll
            for (int t = 0; t < 4; ++t)
                a[t] = *(const bf16x8*)(As + (wm * 64 + t * 16 + l15) * 72 + ko);
            #pragma unroll
            for (int u = 0; u < 2; ++u)
                b[u] = *(const bf16x8*)(Bs + (wn * 32 + u * 16 + l15) * 72 + ko);
            #pragma unroll
            for (int t = 0; t < 4; ++t)
                #pragma unroll
                for (int u = 0; u < 2; ++u)
                    acc[t][u] = __builtin_amdgcn_mfma_f32_16x16x32_bf16(
                        a[t], b[u], acc[t][u], 0, 0, 0);
        }
        __syncthreads();
    }

    // epilogue: C/D layout col=lane&15, row=(lane>>4)*4+reg
    #pragma unroll
    for (int t = 0; t < 4; ++t) {
        int grow = r0 + wm * 64 + t * 16 + q * 4;
        #pragma unroll
        for (int u = 0; u < 2; ++u) {
            int gcol = c0 + wn * 32 + u * 16 + l15;
            float bv = (gcol < bsplit) ? bias[gcol] : bias2[gcol - bsplit];
            #pragma unroll
            for (int i = 0; i < 4; ++i) {
                int r = grow + i;
                if (r >= Nr) continue;
                float v = acc[t][u][i] + bv;
                if (EPI == 1) v = gelu_tanh(v);
                if (EPI == 2) {
                    v += R[(size_t)r * M + gcol];
                    ((float*)Cout)[(size_t)r * M + gcol] = v;
                } else {
                    ((ushort*)Cout)[(size_t)r * M + gcol] = (ushort)f2bf(v);
                }
            }
        }
    }
}

// -------- GAT aggregation v4: register edge indices + depth-2 prefetch --------
__global__ __launch_bounds__(256) void gat_gather(
    const int* __restrict__ deg, const int* __restrict__ esrc,
    const ushort* __restrict__ xlr, const float* __restrict__ att,
    const float* __restrict__ gat_b, ushort* __restrict__ agg, int N)
{
    int node = blockIdx.x * 4 + (threadIdx.x >> 6);
    if (node >= N) return;
    const int lane = threadIdx.x & 63;
    const int half = lane >> 5, sl = lane & 31;
    const int c = sl * 8;

    const uint4 rq = *(const uint4*)(xlr + (size_t)node * 512 + 256 + c);
    const f32x2 r01 = bfpair(rq.x), r23 = bfpair(rq.y);
    const f32x2 r45 = bfpair(rq.z), r67 = bfpair(rq.w);
    const float4 af0 = *(const float4*)(att + c);
    const float4 af1 = *(const float4*)(att + c + 4);
    const f32x2 a01 = {af0.x, af0.y}, a23 = {af0.z, af0.w};
    const f32x2 a45 = {af1.x, af1.y}, a67 = {af1.z, af1.w};

    int dc = deg[node]; dc = dc < CAP ? dc : CAP;
    const int base = node * CAP;
    f32x2 acc01 = {0.f, 0.f}, acc23 = {0.f, 0.f}, acc45 = {0.f, 0.f}, acc67 = {0.f, 0.f};
    float den = 0.f;

    if (dc > 0) {
        int slc = sl < dc ? sl : dc - 1;
        const int idxreg = esrc[base + slc];

        auto getsrc = [&](int e) -> int {
            int idx = e < dc ? e : dc - 1;
            int s = __shfl(idxreg, (lane & 32) | (idx & 31), 64);
            if (idx >= 32) s = esrc[base + idx];
            return s;
        };

        const int iters = (dc + 1) >> 1;
        int e0 = half;
        int s0 = getsrc(e0);
        uint4 lq0 = *(const uint4*)(xlr + (size_t)s0 * 512 + c);
        int e1 = e0 + 2;
        int s1 = getsrc(e1);
        uint4 lq1 = *(const uint4*)(xlr + (size_t)s1 * 512 + c);

        for (int it = 0; it < iters; ++it) {
            const int e2 = e0 + 4;
            const int s2 = getsrc(e2);
            const uint4 lq2 = *(const uint4*)(xlr + (size_t)s2 * 512 + c);

            const f32x2 l01 = bfpair(lq0.x), l23 = bfpair(lq0.y);
            const f32x2 l45 = bfpair(lq0.z), l67 = bfpair(lq0.w);
            f32x2 t, p2;
            t = l01 + r01; p2  = a01 * __builtin_elementwise_max(t, 0.2f * t);
            t = l23 + r23; p2 += a23 * __builtin_elementwise_max(t, 0.2f * t);
            t = l45 + r45; p2 += a45 * __builtin_elementwise_max(t, 0.2f * t);
            t = l67 + r67; p2 += a67 * __builtin_elementwise_max(t, 0.2f * t);
            float p = p2.x + p2.y;
            p += __shfl_xor(p, 1, 64);
            p += __shfl_xor(p, 2, 64);
            p += __shfl_xor(p, 4, 64);
            p += __shfl_xor(p, 8, 64);
            const float ex = (e0 < dc) ? __expf(p) : 0.f;   // O(1) scores: no max-sub
            acc01 += ex * l01; acc23 += ex * l23; acc45 += ex * l45; acc67 += ex * l67;
            den += ex;
            e0 = e1; lq0 = lq1;
            e1 = e2; lq1 = lq2;
        }
    }
    acc01.x += __shfl_xor(acc01.x, 32, 64); acc01.y += __shfl_xor(acc01.y, 32, 64);
    acc23.x += __shfl_xor(acc23.x, 32, 64); acc23.y += __shfl_xor(acc23.y, 32, 64);
    acc45.x += __shfl_xor(acc45.x, 32, 64); acc45.y += __shfl_xor(acc45.y, 32, 64);
    acc67.x += __shfl_xor(acc67.x, 32, 64); acc67.y += __shfl_xor(acc67.y, 32, 64);
    den     += __shfl_xor(den,     32, 64);

    if (half == 0) {
        const float inv = 1.0f / (den + 1e-16f);
        const float4 g0 = *(const float4*)(gat_b + c);
        const float4 g1 = *(const float4*)(gat_b + c + 4);
        uint4 o;
        o.x = f2bf(acc01.x * inv + g0.x) | (f2bf(acc01.y * inv + g0.y) << 16);
        o.y = f2bf(acc23.x * inv + g0.z) | (f2bf(acc23.y * inv + g0.w) << 16);
        o.z = f2bf(acc45.x * inv + g1.x) | (f2bf(acc45.y * inv + g1.y) << 16);
        o.w = f2bf(acc67.x * inv + g1.z) | (f2bf(acc67.y * inv + g1.w) << 16);
        *(uint4*)(agg + (size_t)node * HD + c) = o;
    }
}

extern "C" void kernel_launch(void* const* d_in, const int* in_sizes, int n_in,
                              void* d_out, int out_size, void* d_ws, size_t ws_size,
                              hipStream_t stream) {
    const float* x_in   = (const float*)d_in[0];
    const int*   eidx   = (const int*)d_in[1];
    const float* ln1_g  = (const float*)d_in[2];
    const float* ln1_b  = (const float*)d_in[3];
    const float* Wl     = (const float*)d_in[4];
    const float* bl     = (const float*)d_in[5];
    const float* Wr     = (const float*)d_in[6];
    const float* br     = (const float*)d_in[7];
    const float* att    = (const float*)d_in[8];
    const float* gat_b  = (const float*)d_in[9];
    const float* projW  = (const float*)d_in[10];
    const float* projb  = (const float*)d_in[11];
    const float* ln2_g  = (const float*)d_in[12];
    const float* ln2_b  = (const float*)d_in[13];
    const float* W1     = (const float*)d_in[14];
    const float* b1     = (const float*)d_in[15];
    const float* W2     = (const float*)d_in[16];
    const float* b2     = (const float*)d_in[17];

    const int N = N_NODES;
    const int E = in_sizes[1] / 2;
    const int* src = eidx;
    const int* dst = eidx + E;

    // workspace layout
    char* ws = (char*)d_ws;
    size_t off = 0;
    ushort* xlr  = (ushort*)(ws + off); off += (size_t)N * 512 * 2;   // 51.2 MB
    ushort* agg  = (ushort*)(ws + off); off += (size_t)N * HD * 2;    // 25.6 MB
    ushort* h    = (ushort*)(ws + off); off += (size_t)N * DIM * 2;   // 12.8 MB
    ushort* WlWr_t = (ushort*)(ws + off); off += (size_t)DEPTH * 512 * 128 * 2;
    ushort* pW_t   = (ushort*)(ws + off); off += (size_t)DEPTH * 128 * 256 * 2;
    ushort* W1_t   = (ushort*)(ws + off); off += (size_t)DEPTH * 512 * 128 * 2;
    ushort* W2_t   = (ushort*)(ws + off); off += (size_t)DEPTH * 128 * 512 * 2;
    int* deg     = (int*)(ws + off);    off += (size_t)N * 4;
    int* esrc    = (int*)(ws + off);    off += (size_t)N * CAP * 4;   // 19.2 MB
    ushort* mid  = xlr;   // FFN intermediate [N,512] bf16 aliases xlr

    float* x = (float*)d_out;

    const int nodeBlocks = (N + 3) / 4;
    const dim3 blk(256);
    const int gy = (N + 127) / 128;

    hipMemsetAsync(deg, 0, (size_t)N * 4, stream);
    {
        int total = 458752 + E;
        prep_kernel<<<(total + 255) / 256, blk, 0, stream>>>(
            Wl, Wr, projW, W1, W2, WlWr_t, pW_t, W1_t, W2_t,
            src, dst, deg, esrc, E);
    }

    for (int L = 0; L < DEPTH; ++L) {
        const float* bl_i   = bl + (size_t)L * HD;
        const float* br_i   = br + (size_t)L * HD;
        const float* att_i  = att + (size_t)L * HD;
        const float* gatb_i = gat_b + (size_t)L * HD;
        const float* pb_i   = projb + (size_t)L * DIM;
        const float* b1_i   = b1 + (size_t)L * MLP;
        const float* b2_i   = b2 + (size_t)L * DIM;
        const float* xin_L  = (L == 0) ? x_in : x;   // layer-0 reads input directly

        // h = bf16(LN1(x))
        ln_kernel<<<nodeBlocks, blk, 0, stream>>>(xin_L, ln1_g + L * DIM, ln1_b + L * DIM, h, N);
        // xlr = h @ [Wl|Wr] + [bl|br]  (bf16, M=512, K=128)
        gemm_mfma<0><<<dim3(8, gy), blk, 0, stream>>>(
            h, WlWr_t + (size_t)L * 512 * 128, bl_i, br_i, HD, nullptr, xlr, N, 128, 512);
        // agg = segment-softmax aggregate
        gat_gather<<<nodeBlocks, blk, 0, stream>>>(deg, esrc, xlr, att_i, gatb_i, agg, N);
        // x = xin + agg@projW + projb  (fp32 out to d_out)
        gemm_mfma<2><<<dim3(2, gy), blk, 0, stream>>>(
            agg, pW_t + (size_t)L * 128 * 256, pb_i, pb_i, 1 << 30, xin_L, x, N, 256, 128);
        // h = bf16(LN2(x))
        ln_kernel<<<nodeBlocks, blk, 0, stream>>>(x, ln2_g + L * DIM, ln2_b + L * DIM, h, N);
        // mid = gelu(h@W1 + b1)  (bf16, M=512, K=128)
        gemm_mfma<1><<<dim3(8, gy), blk, 0, stream>>>(
            h, W1_t + (size_t)L * 512 * 128, b1_i, b1_i, 1 << 30, nullptr, mid, N, 128, 512);
        // x = x + mid@W2 + b2  (K=512)
        gemm_mfma<2><<<dim3(2, gy), blk, 0, stream>>>(
            mid, W2_t + (size_t)L * 128 * 512, b2_i, b2_i, 1 << 30, x, x, N, 512, 128);
    }
}

// Round 15
// 556.150 us; speedup vs baseline: 1.0617x; 1.0128x over previous
//
#include <hip/hip_runtime.h>

typedef unsigned int uint;
typedef unsigned short ushort;
typedef __attribute__((ext_vector_type(4))) float f32x4;
typedef __attribute__((ext_vector_type(2))) float f32x2;
typedef __attribute__((ext_vector_type(8))) short bf16x8;

#define N_NODES 50000
#define DIM 128
#define HEADS 2
#define HD 256      // HEADS*DIM
#define MLP 512
#define DEPTH 2
#define CAP 96      // max in-degree bucket capacity (Poisson(16): P(>96) ~ 1e-40)

// ---- bf16 helpers (manual, RNE) ----
__device__ __forceinline__ uint f2bf(float f) {
    uint u = __float_as_uint(f);
    return (u + 0x7FFFu + ((u >> 16) & 1u)) >> 16;   // round-nearest-even
}
__device__ __forceinline__ f32x2 bfpair(uint u) {
    f32x2 r;
    r.x = __uint_as_float(u << 16);
    r.y = __uint_as_float(u & 0xFFFF0000u);
    return r;
}

__device__ __forceinline__ float gelu_tanh(float x) {
    float t = 0.7978845608028654f * (x + 0.044715f * x * x * x);
    float e = __expf(2.0f * t);
    float th = 1.0f - 2.0f / (e + 1.0f);   // tanh(t), overflow-safe
    return 0.5f * x * (1.0f + th);
}

// ---------------- LayerNorm: one wave per node, bf16 output -------------------
__global__ __launch_bounds__(256) void ln_kernel(
    const float* __restrict__ x, const float* __restrict__ g,
    const float* __restrict__ b, ushort* __restrict__ out, int N)
{
    int node = blockIdx.x * 4 + (threadIdx.x >> 6);
    if (node >= N) return;
    int lane = threadIdx.x & 63;
    const float2 v = *(const float2*)(x + (size_t)node * DIM + lane * 2);
    float s = v.x + v.y;
    float s2 = v.x * v.x + v.y * v.y;
    #pragma unroll
    for (int m = 1; m <= 32; m <<= 1) {
        s  += __shfl_xor(s,  m, 64);
        s2 += __shfl_xor(s2, m, 64);
    }
    float mean = s * (1.0f / 128.0f);
    float var  = s2 * (1.0f / 128.0f) - mean * mean;
    float rs = rsqrtf(var + 1e-5f);
    float ox = (v.x - mean) * rs * g[lane * 2]     + b[lane * 2];
    float oy = (v.y - mean) * rs * g[lane * 2 + 1] + b[lane * 2 + 1];
    uint pk = f2bf(ox) | (f2bf(oy) << 16);
    *(uint*)(out + (size_t)node * DIM + lane * 2) = pk;
}

// ------- one-shot weight convert+transpose (all 5 weights, bf16) -------------
__global__ __launch_bounds__(256) void wconv_all(
    const float* __restrict__ Wl, const float* __restrict__ Wr,
    const float* __restrict__ pW, const float* __restrict__ W1,
    const float* __restrict__ W2, ushort* __restrict__ WlWr_t,
    ushort* __restrict__ pW_t, ushort* __restrict__ W1_t,
    ushort* __restrict__ W2_t)
{
    int i = blockIdx.x * 256 + threadIdx.x;
    if (i < 65536) {                       // Wl [D][128][256] -> [D][512][128] rows 0..255
        int l = i >> 15, rem = i & 32767;
        int k = rem >> 8, m = rem & 255;
        WlWr_t[l * 65536 + m * 128 + k] = (ushort)f2bf(Wl[i]);
    } else if (i < 131072) {               // Wr -> rows 256..511
        int j = i - 65536;
        int l = j >> 15, rem = j & 32767;
        int k = rem >> 8, m = rem & 255;
        WlWr_t[l * 65536 + (m + 256) * 128 + k] = (ushort)f2bf(Wr[j]);
    } else if (i < 196608) {               // proj [D][256][128] -> [D][128][256]
        int j = i - 131072;
        int l = j >> 15, rem = j & 32767;
        int k = rem >> 7, m = rem & 127;
        pW_t[l * 32768 + m * 256 + k] = (ushort)f2bf(pW[j]);
    } else if (i < 327680) {               // W1 [D][128][512] -> [D][512][128]
        int j = i - 196608;
        int l = j >> 16, rem = j & 65535;
        int k = rem >> 9, m = rem & 511;
        W1_t[l * 65536 + m * 128 + k] = (ushort)f2bf(W1[j]);
    } else if (i < 458752) {               // W2 [D][512][128] -> [D][128][512]
        int j = i - 327680;
        int l = j >> 16, rem = j & 65535;
        int k = rem >> 7, m = rem & 127;
        W2_t[l * 65536 + m * 512 + k] = (ushort)f2bf(W2[j]);
    }
}

// ---------------- bf16 MFMA GEMM (R4 config): A[Nr][K] @ Bt[M][K]^T -----------
// 128x64 tile, BK=64, 4 waves (2x2), LDS pad 72 (2-way bank alias = free).
// EPI: 0=bias->bf16, 1=bias+gelu->bf16, 2=bias+residual->fp32.
template<int EPI>
__global__ __launch_bounds__(256) void gemm_mfma(
    const ushort* __restrict__ A, const ushort* __restrict__ Bt,
    const float* __restrict__ bias, const float* __restrict__ bias2, int bsplit,
    const float* __restrict__ R, void* __restrict__ Cout, int Nr, int K, int M)
{
    __shared__ ushort As[128 * 72];
    __shared__ ushort Bs[64 * 72];
    const int tid = threadIdx.x;
    const int wave = tid >> 6, lane = tid & 63;
    const int wm = wave >> 1, wn = wave & 1;
    const int r0 = blockIdx.y * 128;
    const int c0 = blockIdx.x * 64;
    const int l15 = lane & 15, q = lane >> 4;

    f32x4 acc[4][2];
    #pragma unroll
    for (int t = 0; t < 4; ++t)
        #pragma unroll
        for (int u = 0; u < 2; ++u) {
            f32x4 z = {0.f, 0.f, 0.f, 0.f};
            acc[t][u] = z;
        }

    for (int k0 = 0; k0 < K; k0 += 64) {
        #pragma unroll
        for (int p = 0; p < 4; ++p) {
            int flat = p * 256 + tid;
            int row = flat >> 3, c8 = flat & 7;
            int gr = r0 + row; gr = gr < Nr ? gr : Nr - 1;
            uint4 v = *(const uint4*)(A + (size_t)gr * K + k0 + c8 * 8);
            *(uint4*)(As + row * 72 + c8 * 8) = v;
        }
        #pragma unroll
        for (int p = 0; p < 2; ++p) {
            int flat = p * 256 + tid;
            int row = flat >> 3, c8 = flat & 7;
            uint4 v = *(const uint4*)(Bt + (size_t)(c0 + row) * K + k0 + c8 * 8);
            *(uint4*)(Bs + row * 72 + c8 * 8) = v;
        }
        __syncthreads();
        #pragma unroll
        for (int kh = 0; kh < 2; ++kh) {
            const int ko = kh * 32 + q * 8;
            bf16x8 a[4], b[2];
            #pragma unroll
            for (int t = 0; t < 4; ++t)
                a[t] = *(const bf16x8*)(As + (wm * 64 + t * 16 + l15) * 72 + ko);
            #pragma unroll
            for (int u = 0; u < 2; ++u)
                b[u] = *(const bf16x8*)(Bs + (wn * 32 + u * 16 + l15) * 72 + ko);
            #pragma unroll
            for (int t = 0; t < 4; ++t)
                #pragma unroll
                for (int u = 0; u < 2; ++u)
                    acc[t][u] = __builtin_amdgcn_mfma_f32_16x16x32_bf16(
                        a[t], b[u], acc[t][u], 0, 0, 0);
        }
        __syncthreads();
    }

    // epilogue: C/D layout col=lane&15, row=(lane>>4)*4+reg
    #pragma unroll
    for (int t = 0; t < 4; ++t) {
        int grow = r0 + wm * 64 + t * 16 + q * 4;
        #pragma unroll
        for (int u = 0; u < 2; ++u) {
            int gcol = c0 + wn * 32 + u * 16 + l15;
            float bv = (gcol < bsplit) ? bias[gcol] : bias2[gcol - bsplit];
            #pragma unroll
            for (int i = 0; i < 4; ++i) {
                int r = grow + i;
                if (r >= Nr) continue;
                float v = acc[t][u][i] + bv;
                if (EPI == 1) v = gelu_tanh(v);
                if (EPI == 2) {
                    v += R[(size_t)r * M + gcol];
                    ((float*)Cout)[(size_t)r * M + gcol] = v;
                } else {
                    ((ushort*)Cout)[(size_t)r * M + gcol] = (ushort)f2bf(v);
                }
            }
        }
    }
}

// ---------------- scan-free CSR: atomic bucket fill (ushort payload) ----------
// esrc stored as ushort (N < 65536): halves scatter footprint and write
// amplification (192 B rows, more slots per 64 B line -> better L2 merging).
__global__ __launch_bounds__(256) void bucket_kernel(
    const int* __restrict__ src, const int* __restrict__ dst,
    int* __restrict__ deg, ushort* __restrict__ esrc, int E)
{
    int e = blockIdx.x * 256 + threadIdx.x;
    if (e >= E) return;
    int d = dst[e];
    int pos = atomicAdd(&deg[d], 1);
    if (pos < CAP) esrc[(size_t)d * CAP + pos] = (ushort)src[e];
}

// -------- GAT aggregation v4: register edge indices + depth-2 prefetch --------
__global__ __launch_bounds__(256) void gat_gather(
    const int* __restrict__ deg, const ushort* __restrict__ esrc,
    const ushort* __restrict__ xlr, const float* __restrict__ att,
    const float* __restrict__ gat_b, ushort* __restrict__ agg, int N)
{
    int node = blockIdx.x * 4 + (threadIdx.x >> 6);
    if (node >= N) return;
    const int lane = threadIdx.x & 63;
    const int half = lane >> 5, sl = lane & 31;
    const int c = sl * 8;

    const uint4 rq = *(const uint4*)(xlr + (size_t)node * 512 + 256 + c);
    const f32x2 r01 = bfpair(rq.x), r23 = bfpair(rq.y);
    const f32x2 r45 = bfpair(rq.z), r67 = bfpair(rq.w);
    const float4 af0 = *(const float4*)(att + c);
    const float4 af1 = *(const float4*)(att + c + 4);
    const f32x2 a01 = {af0.x, af0.y}, a23 = {af0.z, af0.w};
    const f32x2 a45 = {af1.x, af1.y}, a67 = {af1.z, af1.w};

    int dc = deg[node]; dc = dc < CAP ? dc : CAP;
    const int base = node * CAP;
    f32x2 acc01 = {0.f, 0.f}, acc23 = {0.f, 0.f}, acc45 = {0.f, 0.f}, acc67 = {0.f, 0.f};
    float den = 0.f;

    if (dc > 0) {
        int slc = sl < dc ? sl : dc - 1;
        const int idxreg = esrc[base + slc];   // zero-extended ushort

        auto getsrc = [&](int e) -> int {
            int idx = e < dc ? e : dc - 1;
            int s = __shfl(idxreg, (lane & 32) | (idx & 31), 64);
            if (idx >= 32) s = esrc[base + idx];
            return s;
        };

        const int iters = (dc + 1) >> 1;
        int e0 = half;
        int s0 = getsrc(e0);
        uint4 lq0 = *(const uint4*)(xlr + (size_t)s0 * 512 + c);
        int e1 = e0 + 2;
        int s1 = getsrc(e1);
        uint4 lq1 = *(const uint4*)(xlr + (size_t)s1 * 512 + c);

        for (int it = 0; it < iters; ++it) {
            const int e2 = e0 + 4;
            const int s2 = getsrc(e2);
            const uint4 lq2 = *(const uint4*)(xlr + (size_t)s2 * 512 + c);

            const f32x2 l01 = bfpair(lq0.x), l23 = bfpair(lq0.y);
            const f32x2 l45 = bfpair(lq0.z), l67 = bfpair(lq0.w);
            f32x2 t, p2;
            t = l01 + r01; p2  = a01 * __builtin_elementwise_max(t, 0.2f * t);
            t = l23 + r23; p2 += a23 * __builtin_elementwise_max(t, 0.2f * t);
            t = l45 + r45; p2 += a45 * __builtin_elementwise_max(t, 0.2f * t);
            t = l67 + r67; p2 += a67 * __builtin_elementwise_max(t, 0.2f * t);
            float p = p2.x + p2.y;
            p += __shfl_xor(p, 1, 64);
            p += __shfl_xor(p, 2, 64);
            p += __shfl_xor(p, 4, 64);
            p += __shfl_xor(p, 8, 64);
            const float ex = (e0 < dc) ? __expf(p) : 0.f;   // O(1) scores: no max-sub
            acc01 += ex * l01; acc23 += ex * l23; acc45 += ex * l45; acc67 += ex * l67;
            den += ex;
            e0 = e1; lq0 = lq1;
            e1 = e2; lq1 = lq2;
        }
    }
    acc01.x += __shfl_xor(acc01.x, 32, 64); acc01.y += __shfl_xor(acc01.y, 32, 64);
    acc23.x += __shfl_xor(acc23.x, 32, 64); acc23.y += __shfl_xor(acc23.y, 32, 64);
    acc45.x += __shfl_xor(acc45.x, 32, 64); acc45.y += __shfl_xor(acc45.y, 32, 64);
    acc67.x += __shfl_xor(acc67.x, 32, 64); acc67.y += __shfl_xor(acc67.y, 32, 64);
    den     += __shfl_xor(den,     32, 64);

    if (half == 0) {
        const float inv = 1.0f / (den + 1e-16f);
        const float4 g0 = *(const float4*)(gat_b + c);
        const float4 g1 = *(const float4*)(gat_b + c + 4);
        uint4 o;
        o.x = f2bf(acc01.x * inv + g0.x) | (f2bf(acc01.y * inv + g0.y) << 16);
        o.y = f2bf(acc23.x * inv + g0.z) | (f2bf(acc23.y * inv + g0.w) << 16);
        o.z = f2bf(acc45.x * inv + g1.x) | (f2bf(acc45.y * inv + g1.y) << 16);
        o.w = f2bf(acc67.x * inv + g1.z) | (f2bf(acc67.y * inv + g1.w) << 16);
        *(uint4*)(agg + (size_t)node * HD + c) = o;
    }
}

extern "C" void kernel_launch(void* const* d_in, const int* in_sizes, int n_in,
                              void* d_out, int out_size, void* d_ws, size_t ws_size,
                              hipStream_t stream) {
    const float* x_in   = (const float*)d_in[0];
    const int*   eidx   = (const int*)d_in[1];
    const float* ln1_g  = (const float*)d_in[2];
    const float* ln1_b  = (const float*)d_in[3];
    const float* Wl     = (const float*)d_in[4];
    const float* bl     = (const float*)d_in[5];
    const float* Wr     = (const float*)d_in[6];
    const float* br     = (const float*)d_in[7];
    const float* att    = (const float*)d_in[8];
    const float* gat_b  = (const float*)d_in[9];
    const float* projW  = (const float*)d_in[10];
    const float* projb  = (const float*)d_in[11];
    const float* ln2_g  = (const float*)d_in[12];
    const float* ln2_b  = (const float*)d_in[13];
    const float* W1     = (const float*)d_in[14];
    const float* b1     = (const float*)d_in[15];
    const float* W2     = (const float*)d_in[16];
    const float* b2     = (const float*)d_in[17];

    const int N = N_NODES;
    const int E = in_sizes[1] / 2;
    const int* src = eidx;
    const int* dst = eidx + E;

    // workspace layout
    char* ws = (char*)d_ws;
    size_t off = 0;
    ushort* xlr  = (ushort*)(ws + off); off += (size_t)N * 512 * 2;   // 51.2 MB
    ushort* agg  = (ushort*)(ws + off); off += (size_t)N * HD * 2;    // 25.6 MB
    ushort* h    = (ushort*)(ws + off); off += (size_t)N * DIM * 2;   // 12.8 MB
    ushort* WlWr_t = (ushort*)(ws + off); off += (size_t)DEPTH * 512 * 128 * 2;
    ushort* pW_t   = (ushort*)(ws + off); off += (size_t)DEPTH * 128 * 256 * 2;
    ushort* W1_t   = (ushort*)(ws + off); off += (size_t)DEPTH * 512 * 128 * 2;
    ushort* W2_t   = (ushort*)(ws + off); off += (size_t)DEPTH * 128 * 512 * 2;
    int* deg     = (int*)(ws + off);    off += (size_t)N * 4;
    ushort* esrc = (ushort*)(ws + off); off += (size_t)N * CAP * 2;   // 9.6 MB
    ushort* mid  = xlr;   // FFN intermediate [N,512] bf16 aliases xlr

    float* x = (float*)d_out;

    const int nodeBlocks = (N + 3) / 4;
    const dim3 blk(256);
    const int gy = (N + 127) / 128;

    wconv_all<<<(458752 + 255) / 256, blk, 0, stream>>>(
        Wl, Wr, projW, W1, W2, WlWr_t, pW_t, W1_t, W2_t);

    hipMemsetAsync(deg, 0, (size_t)N * 4, stream);
    bucket_kernel<<<(E + 255) / 256, blk, 0, stream>>>(src, dst, deg, esrc, E);

    for (int L = 0; L < DEPTH; ++L) {
        const float* bl_i   = bl + (size_t)L * HD;
        const float* br_i   = br + (size_t)L * HD;
        const float* att_i  = att + (size_t)L * HD;
        const float* gatb_i = gat_b + (size_t)L * HD;
        const float* pb_i   = projb + (size_t)L * DIM;
        const float* b1_i   = b1 + (size_t)L * MLP;
        const float* b2_i   = b2 + (size_t)L * DIM;
        const float* xin_L  = (L == 0) ? x_in : x;   // layer-0 reads input directly

        // h = bf16(LN1(x))
        ln_kernel<<<nodeBlocks, blk, 0, stream>>>(xin_L, ln1_g + L * DIM, ln1_b + L * DIM, h, N);
        // xlr = h @ [Wl|Wr] + [bl|br]  (bf16, M=512, K=128)
        gemm_mfma<0><<<dim3(8, gy), blk, 0, stream>>>(
            h, WlWr_t + (size_t)L * 512 * 128, bl_i, br_i, HD, nullptr, xlr, N, 128, 512);
        // agg = segment-softmax aggregate
        gat_gather<<<nodeBlocks, blk, 0, stream>>>(deg, esrc, xlr, att_i, gatb_i, agg, N);
        // x = xin + agg@projW + projb  (fp32 out to d_out)
        gemm_mfma<2><<<dim3(2, gy), blk, 0, stream>>>(
            agg, pW_t + (size_t)L * 128 * 256, pb_i, pb_i, 1 << 30, xin_L, x, N, 256, 128);
        // h = bf16(LN2(x))
        ln_kernel<<<nodeBlocks, blk, 0, stream>>>(x, ln2_g + L * DIM, ln2_b + L * DIM, h, N);
        // mid = gelu(h@W1 + b1)  (bf16, M=512, K=128)
        gemm_mfma<1><<<dim3(8, gy), blk, 0, stream>>>(
            h, W1_t + (size_t)L * 512 * 128, b1_i, b1_i, 1 << 30, nullptr, mid, N, 128, 512);
        // x = x + mid@W2 + b2  (K=512)
        gemm_mfma<2><<<dim3(2, gy), blk, 0, stream>>>(
            mid, W2_t + (size_t)L * 128 * 512, b2_i, b2_i, 1 << 30, x, x, N, 512, 128);
    }
}